// Round 11
// baseline (378.544 us; speedup 1.0000x reference)
//
#include <hip/hip_runtime.h>
#include <hip/hip_fp16.h>
#include <math.h>

#define T_STEPS 24
#define BATCH   128
#define DGI     256
#define DHI     512
#define S_ITERS 3
#define LAMBDA  0.95f
#define ETA     0.5f
#define EPS_A   1e-6f
#define LN_EPS  1e-5f
#define EPS_N   1e-6f
#define HIST_MAX 23
#define NG4      6    // ceil(24/4) groups of 4 s-slots

// dot2: fp16x2 . fp16x2 + fp32 -> fp32
static __device__ __forceinline__ float dot2(unsigned int a, unsigned int b, float c) {
#if __has_builtin(__builtin_amdgcn_fdot2)
    typedef _Float16 h2v __attribute__((ext_vector_type(2)));
    return __builtin_amdgcn_fdot2(__builtin_bit_cast(h2v, a),
                                  __builtin_bit_cast(h2v, b), c, false);
#else
    const __half2 ha = __builtin_bit_cast(__half2, a);
    const __half2 hb = __builtin_bit_cast(__half2, b);
    const float2 fa = __half22float2(ha);
    const float2 fb = __half22float2(hb);
    return fmaf(fa.x, fb.x, fmaf(fa.y, fb.y, c));
#endif
}

static __device__ __forceinline__ unsigned int rdlane_u(unsigned int v, int l) {
#if __has_builtin(__builtin_amdgcn_readlane)
    return __builtin_amdgcn_readlane(v, l);
#else
    return __shfl((int)v, l, 64);
#endif
}
static __device__ __forceinline__ float rdlane_f(float v, int l) {
    return __uint_as_float(rdlane_u(__float_as_uint(v), l));
}

static __device__ __forceinline__ float wsum(float v) {
    #pragma unroll
    for (int off = 32; off > 0; off >>= 1) v += __shfl_xor(v, off, 64);
    return v;
}
static __device__ __forceinline__ float dot8(float4 a, float4 b, float4 c, float4 d) {
    float r = a.x * c.x;
    r = fmaf(a.y, c.y, r); r = fmaf(a.z, c.z, r); r = fmaf(a.w, c.w, r);
    r = fmaf(b.x, d.x, r); r = fmaf(b.y, d.y, r); r = fmaf(b.z, d.z, r);
    r = fmaf(b.w, d.w, r);
    return r;
}
static __device__ __forceinline__ float sum8(float4 a, float4 b) {
    return ((a.x + a.y) + (a.z + a.w)) + ((b.x + b.y) + (b.z + b.w));
}

// ---------------------------------------------------------------------------
// Merged prep: blocks 0..255 pack W_h fp16 pairs (P[j2*512+i]); blocks
// 256..383 transpose W_g tile-wise into WgT[j][i]. One launch instead of two.
// ---------------------------------------------------------------------------
__global__ __launch_bounds__(512)
void prep_k(const float* __restrict__ Wh, unsigned int* __restrict__ P,
            const float* __restrict__ Wg, float* __restrict__ WgT) {
    __shared__ float tile[32][33];
    const int blk = blockIdx.x;
    if (blk < 256) {
        const int j2 = blk;
        const int i  = threadIdx.x;
        const float2 w = *(const float2*)(Wh + (size_t)i * DHI + 2 * j2);
        const __half2 h = __floats2half2_rn(w.x, w.y);
        P[(size_t)j2 * DHI + i] = __builtin_bit_cast(unsigned int, h);
    } else {
        const int tb = blk - 256;            // [0,128): 8 x 16 tile grid
        const int c0 = (tb & 7) * 32;        // j (DGI) tile
        const int r0 = (tb >> 3) * 32;       // i (DHI) tile
        const int tx = threadIdx.x & 31;
        const int ty = (threadIdx.x >> 5) & 7;
        const bool act = threadIdx.x < 256;
        if (act) {
            #pragma unroll
            for (int i = 0; i < 32; i += 8)
                tile[ty + i][tx] = Wg[(size_t)(r0 + ty + i) * DGI + (c0 + tx)];
        }
        __syncthreads();
        if (act) {
            #pragma unroll
            for (int i = 0; i < 32; i += 8)
                WgT[(size_t)(c0 + ty + i) * DHI + (r0 + tx)] = tile[tx][ty + i];
        }
    }
}

// ---------------------------------------------------------------------------
// zproj[b][t][i] = sum_j WgT[j][i] * z[t][b][j]  (coalesced, fp32-exact)
// grid (BATCH, 3), 512 threads, 8 timesteps per block.
// ---------------------------------------------------------------------------
__global__ __launch_bounds__(512)
void zproj_k(const float* __restrict__ z_seq, const float* __restrict__ WgT,
             float* __restrict__ zp) {
    __shared__ __align__(16) float  sh_z[8][DGI];
    __shared__ __align__(16) float4 sh_acc[8][4][128];
    const int b    = blockIdx.x;
    const int t0   = blockIdx.y * 8;
    const int tid  = threadIdx.x;
    const int lane = tid & 63;
    const int wave = tid >> 6;
    {
        const float4* src =
            (const float4*)(z_seq + ((size_t)(t0 + wave) * BATCH + b) * DGI);
        ((float4*)sh_z[wave])[lane] = src[lane];
    }
    __syncthreads();

    const int i4  = tid & 127;
    const int jg  = tid >> 7;
    const int jlo = jg * 64;
    float zreg[8];
    #pragma unroll
    for (int tt = 0; tt < 8; ++tt) zreg[tt] = sh_z[tt][jlo + lane];

    float4 acc[8];
    #pragma unroll
    for (int tt = 0; tt < 8; ++tt) acc[tt] = make_float4(0.f, 0.f, 0.f, 0.f);

    const float4* w4 = (const float4*)WgT;
    #pragma unroll 4
    for (int jj = 0; jj < 64; ++jj) {
        const float4 wv = w4[(size_t)(jlo + jj) * 128 + i4];
        #pragma unroll
        for (int tt = 0; tt < 8; ++tt) {
            const float zv = rdlane_f(zreg[tt], jj);
            acc[tt].x = fmaf(wv.x, zv, acc[tt].x);
            acc[tt].y = fmaf(wv.y, zv, acc[tt].y);
            acc[tt].z = fmaf(wv.z, zv, acc[tt].z);
            acc[tt].w = fmaf(wv.w, zv, acc[tt].w);
        }
    }
    #pragma unroll
    for (int tt = 0; tt < 8; ++tt) sh_acc[tt][jg][i4] = acc[tt];
    __syncthreads();

    const float* af = (const float*)sh_acc;
    #pragma unroll
    for (int tt = 0; tt < 8; ++tt) {
        const int o = tt * 4 * 512;
        const float v = (af[o + tid] + af[o + 512 + tid]) +
                        (af[o + 1024 + tid] + af[o + 1536 + tid]);
        zp[((size_t)b * T_STEPS + t0 + tt) * DHI + tid] = v;
    }
}

// ---------------------------------------------------------------------------
// Recurrence v4. One block per batch element, 512 threads.
// NEW: first 32 of each thread's 64 GEMV weight uint4 are STEP-INVARIANT ->
// loaded ONCE into registers before the t-loop (halves the per-step L2
// stream); second half streamed via 2x4 double-buffer, issued before the
// register-half compute so its latency hides under VALU.
// ---------------------------------------------------------------------------
__global__ __launch_bounds__(512)
void rnn_v4(const float* __restrict__ zp,
            const unsigned int* __restrict__ P,
            const float* __restrict__ b_h,
            const float* __restrict__ gamma,
            const float* __restrict__ beta,
            const float* __restrict__ alpha_fw,
            float* __restrict__ out) {
    __shared__ __align__(16) float  sh_hist[HIST_MAX][DHI];
    __shared__ __align__(16) float4 sh_hT4[NG4][DHI];
    __shared__ __align__(16) float4 sh_G4[NG4][64];
    __shared__ __align__(16) float  sh_hs[2][DHI];
    __shared__ __align__(16) float  sh_hb[DHI];
    __shared__ __align__(16) float4 sh_part[4][128];
    __shared__ __align__(16) unsigned int sh_h2[DHI / 2];
    __shared__ __align__(16) float  sh_coef[32];
    __shared__ __align__(16) float  sh_dot[32];
    __shared__ __align__(16) float  sh_dhb[32];
    __shared__ __align__(16) float  sh_rsum[32];
    __shared__ float sh_misc[2];

    const int tid  = threadIdx.x;
    const int lane = tid & 63;
    const int wave = tid >> 6;
    const int b    = blockIdx.x;

    const float bh_r = b_h[tid];
    const float g_r  = gamma[tid];
    const float bt_r = beta[tid];

    float kpow;
    {
        const float a  = alpha_fw[0];
        const float ax = fabsf(a);
        const float sp = (ax > 20.f) ? ax : log1pf(expf(ax));
        kpow = (a >= 0.f) ? (1.f + sp) : (1.f / (1.f + sp));
    }

    // step-invariant GEMV setup + pinned first-half weights (128 VGPR)
    const int i4  = tid & 127;
    const int jg  = tid >> 7;
    const uint4* __restrict__ wp = (const uint4*)P;
    const int wbase = (jg << 6) * 128 + i4;
    uint4 Wpre[32];
    #pragma unroll
    for (int k = 0; k < 32; ++k) Wpre[k] = wp[wbase + k * 128];

    {
        const float4 z4 = make_float4(0.f, 0.f, 0.f, 0.f);
        for (int i = tid; i < NG4 * DHI; i += DHI) ((float4*)sh_hT4)[i] = z4;
        if (tid < NG4 * 64) ((float4*)sh_G4)[tid] = z4;
        if (tid < 32) { sh_coef[tid] = 0.f; sh_dot[tid] = 0.f;
                        sh_dhb[tid]  = 0.f; sh_rsum[tid] = 0.f; }
        if (tid < 2) sh_misc[tid] = 0.f;
    }
    __syncthreads();

    int   p = 0;
    float hs_i = 0.f, hbase_i = 0.f;
    const size_t zbase = (size_t)b * T_STEPS * DHI + tid;
    float zv = zp[zbase];

    for (int t = 0; t < T_STEPS; ++t) {
        // ---- GEMV: h_base = b_h + Wh.h + Wg.z
        if (t > 0) {
            const unsigned int hreg = sh_h2[(jg << 6) | lane];
            float4 acc = make_float4(0.f, 0.f, 0.f, 0.f);
            uint4 cbuf[2][4];
            // issue first streamed chunk (jj=32..35) before register compute
            #pragma unroll
            for (int k = 0; k < 4; ++k) cbuf[0][k] = wp[wbase + (32 + k) * 128];
            // register half (jj=0..31), pure VALU — hides chunk-0 latency
            #pragma unroll
            for (int jj = 0; jj < 32; ++jj) {
                const unsigned int hh = rdlane_u(hreg, jj);
                const uint4 wv = Wpre[jj];
                acc.x = dot2(wv.x, hh, acc.x);
                acc.y = dot2(wv.y, hh, acc.y);
                acc.z = dot2(wv.z, hh, acc.z);
                acc.w = dot2(wv.w, hh, acc.w);
            }
            // streamed half (jj=32..63), 8 chunks of 4, double-buffered
            #pragma unroll
            for (int ch = 0; ch < 8; ++ch) {
                if (ch < 7) {
                    #pragma unroll
                    for (int k = 0; k < 4; ++k)
                        cbuf[(ch + 1) & 1][k] = wp[wbase + (36 + ch * 4 + k) * 128];
                }
                #pragma unroll
                for (int k = 0; k < 4; ++k) {
                    const int jj = 32 + ch * 4 + k;
                    const unsigned int hh = rdlane_u(hreg, jj);
                    const uint4 wv = cbuf[ch & 1][k];
                    acc.x = dot2(wv.x, hh, acc.x);
                    acc.y = dot2(wv.y, hh, acc.y);
                    acc.z = dot2(wv.z, hh, acc.z);
                    acc.w = dot2(wv.w, hh, acc.w);
                }
            }
            sh_part[jg][i4] = acc;
            __syncthreads();                                  // barrier A
            const float* pp = (const float*)sh_part;
            hbase_i = bh_r + zv +
                      ((pp[tid] + pp[512 + tid]) + (pp[1024 + tid] + pp[1536 + tid]));
        } else {
            hbase_i = bh_r + zv;
        }
        sh_hb[tid] = hbase_i;
        hs_i = fmaxf(hbase_i, 0.f);
        p ^= 1;
        sh_hs[p][tid] = hs_i;
        __syncthreads();                                      // barrier 1

        if (t + 1 < T_STEPS) zv = zp[zbase + (size_t)(t + 1) * DHI];

        const int niter = (t == 0) ? 1 : S_ITERS;
        for (int it = 0; it < niter; ++it) {
            // ---- dots phase: wave-split over s in [0..t]
            {
                const float4* h4p = (const float4*)sh_hs[p];
                const float4 ha = h4p[lane], hc = h4p[64 + lane];
                float4 ba, bc;
                if (it == 0) {
                    const float4* b4p = (const float4*)sh_hb;
                    ba = b4p[lane]; bc = b4p[64 + lane];
                }
                for (int s = wave; s <= t; s += 8) {
                    if (s == t) {
                        float d = dot8(ha, hc, ha, hc);
                        if (it == 0) {
                            float s1 = sum8(ba, bc);
                            float s2 = dot8(ba, bc, ba, bc);
                            d = wsum(d); s1 = wsum(s1); s2 = wsum(s2);
                            if (lane == 0) { sh_dot[t] = d;
                                             sh_misc[0] = s1; sh_misc[1] = s2; }
                        } else {
                            d = wsum(d);
                            if (lane == 0) sh_dot[t] = d;
                        }
                    } else {
                        const float4* v4 = (const float4*)sh_hist[s];
                        const float4 va = v4[lane], vc = v4[64 + lane];
                        float d = dot8(va, vc, ha, hc);
                        if (it == 0) {
                            float e = dot8(va, vc, ba, bc);
                            d = wsum(d); e = wsum(e);
                            if (lane == 0) { sh_dot[s] = d; sh_dhb[s] = e; }
                        } else {
                            d = wsum(d);
                            if (lane == 0) sh_dot[s] = d;
                        }
                    }
                }
            }
            __syncthreads();                                  // barrier 2

            // ---- scalar phase (algebraic LN)
            float pa = 0.f, SA = 0.f, SHA = 0.f, gsum = 0.f, Ah = 0.f;
            {
                const float4* c4 = (const float4*)sh_coef;
                const float4* d4 = (const float4*)sh_dot;
                const float4* e4 = (const float4*)sh_dhb;
                const float4* r4 = (const float4*)sh_rsum;
                const int ng = (t + 4) >> 2;
                for (int g = 0; g < ng; ++g) {
                    const float4 cc = c4[g], dd = d4[g], ee = e4[g], rr = r4[g];
                    const float4 gg = sh_G4[g][lane];
                    const float4 hv = sh_hT4[g][tid];
                    const float w0 = cc.x * dd.x, w1 = cc.y * dd.y;
                    const float w2 = cc.z * dd.z, w3 = cc.w * dd.w;
                    pa   = fmaf(w0, dd.x, fmaf(w1, dd.y, fmaf(w2, dd.z, fmaf(w3, dd.w, pa))));
                    SA   = fmaf(w0, rr.x, fmaf(w1, rr.y, fmaf(w2, rr.z, fmaf(w3, rr.w, SA))));
                    SHA  = fmaf(w0, ee.x, fmaf(w1, ee.y, fmaf(w2, ee.z, fmaf(w3, ee.w, SHA))));
                    gsum = fmaf(w0, gg.x, fmaf(w1, gg.y, fmaf(w2, gg.z, fmaf(w3, gg.w, gsum))));
                    Ah   = fmaf(w0, hv.x, fmaf(w1, hv.y, fmaf(w2, hv.z, fmaf(w3, hv.w, Ah))));
                }
            }
            const float wl = (lane < 32) ? sh_coef[lane] * sh_dot[lane] : 0.f;
            const float pb = wsum(wl * gsum);

            const float n1 = fmaxf(sqrtf(sh_dot[t]), EPS_N);
            const float n2 = fmaxf(sqrtf(fmaxf(pb, 0.f)), EPS_N);
            float R = pa / (n1 * n2);
            R = fminf(fmaxf(R, 0.f), 1.f);
            const float alpha = 1.f - __powf(1.f - R, kpow);
            const float c = 1.f - alpha * alpha;

            const float S1 = sh_misc[0], S2 = sh_misc[1];
            const float mean = (c * S1 + alpha * SA) * (1.f / DHI);
            float var = (c * c * S2 + 2.f * c * alpha * SHA + alpha * alpha * pb)
                        * (1.f / DHI) - mean * mean;
            var = fmaxf(var, 0.f);
            const float rstd = rsqrtf(var + LN_EPS);

            const float y = fmaf(c, hbase_i, alpha * Ah);
            hs_i = fmaxf(fmaf((y - mean) * rstd, g_r, bt_r), 0.f);
            p ^= 1;
            sh_hs[p][tid] = hs_i;
            if (it == niter - 1 && t + 1 < T_STEPS) {
                const float partner = __shfl_xor(hs_i, 1);
                if (!(tid & 1)) {
                    const __half2 h2 = __floats2half2_rn(hs_i, partner);
                    sh_h2[tid >> 1] = __builtin_bit_cast(unsigned int, h2);
                }
            }
            __syncthreads();                                  // barrier 4
        }

        if (t < T_STEPS - 1) {
            // ---- append: Gram row + coef + rowsum + both hist layouts
            const float4* h4p = (const float4*)sh_hs[p];
            const float4 ha = h4p[lane], hc = h4p[64 + lane];
            for (int s = wave; s <= t; s += 8) {
                if (s == t) {
                    float d  = dot8(ha, hc, ha, hc);
                    float rs = sum8(ha, hc);
                    d = wsum(d); rs = wsum(rs);
                    if (lane == 0) {
                        ((float*)&sh_G4[t >> 2][t])[t & 3] = d;
                        sh_coef[t] = ETA / (d + EPS_A);
                        sh_rsum[t] = rs;
                    }
                } else {
                    const float4* v4 = (const float4*)sh_hist[s];
                    const float4 va = v4[lane], vc = v4[64 + lane];
                    float d = dot8(va, vc, ha, hc);
                    d = wsum(d);
                    if (lane == 0) {
                        ((float*)&sh_G4[t >> 2][s])[t & 3] = d;
                        ((float*)&sh_G4[s >> 2][t])[s & 3] = d;
                    }
                }
            }
            if (tid < t) sh_coef[tid] *= LAMBDA;
            sh_hist[t][tid] = hs_i;
            ((float*)&sh_hT4[t >> 2][tid])[t & 3] = hs_i;
        } else {
            out[(size_t)b * DHI + tid] = hs_i;
        }
    }
}

// ---------------------------------------------------------------------------
// Fallback (ws too small): self-contained fp32 path (known-good).
// ---------------------------------------------------------------------------
__global__ __launch_bounds__(512)
void corernn_fb(const float* __restrict__ z_seq, const float* __restrict__ Wh,
                const float* __restrict__ Wg, const float* __restrict__ b_h,
                const float* __restrict__ gamma, const float* __restrict__ beta,
                const float* __restrict__ alpha_fw, float* __restrict__ out) {
    __shared__ __align__(16) float sh_hist[HIST_MAX][DHI];
    __shared__ __align__(16) float sh_hs[2][DHI];
    __shared__ __align__(16) float sh_G[HIST_MAX][64];
    __shared__ float  sh_coef[32];
    __shared__ float  sh_dot[32];
    __shared__ float2 sh_red[8];
    __shared__ __align__(16) float sh_z[DGI];

    const int tid  = threadIdx.x;
    const int lane = tid & 63;
    const int wave = tid >> 6;
    const int b    = blockIdx.x;
    const float bh_r = b_h[tid];
    const float g_r  = gamma[tid];
    const float bt_r = beta[tid];
    float kpow;
    {
        const float a  = alpha_fw[0];
        const float ax = fabsf(a);
        const float sp = (ax > 20.f) ? ax : log1pf(expf(ax));
        kpow = (a >= 0.f) ? (1.f + sp) : (1.f / (1.f + sp));
    }
    for (int i = tid; i < HIST_MAX * 64; i += DHI) ((float*)sh_G)[i] = 0.f;
    if (tid < DGI) sh_z[tid] = z_seq[(size_t)b * DGI + tid];
    __syncthreads();

    int p = 0;
    float hs_i = 0.f, hbase_i = 0.f;
    for (int t = 0; t < T_STEPS; ++t) {
        float a0 = bh_r, a1 = 0.f, a2 = 0.f, a3 = 0.f;
        {
            const float4* wrow = (const float4*)(Wg + (size_t)tid * DGI);
            const float4* z4   = (const float4*)sh_z;
            #pragma unroll 4
            for (int j4 = 0; j4 < DGI / 4; ++j4) {
                const float4 w = wrow[j4]; const float4 h = z4[j4];
                a0 = fmaf(w.x, h.x, a0); a1 = fmaf(w.y, h.y, a1);
                a2 = fmaf(w.z, h.z, a2); a3 = fmaf(w.w, h.w, a3);
            }
        }
        if (t > 0) {
            const float4* wrow = (const float4*)(Wh + (size_t)tid * DHI);
            const float4* h4   = (const float4*)sh_hs[p];
            #pragma unroll 4
            for (int j4 = 0; j4 < DHI / 4; ++j4) {
                const float4 w = wrow[j4]; const float4 h = h4[j4];
                a0 = fmaf(w.x, h.x, a0); a1 = fmaf(w.y, h.y, a1);
                a2 = fmaf(w.z, h.z, a2); a3 = fmaf(w.w, h.w, a3);
            }
        }
        hbase_i = (a0 + a1) + (a2 + a3);
        hs_i = fmaxf(hbase_i, 0.f);
        p ^= 1; sh_hs[p][tid] = hs_i;
        __syncthreads();

        const int niter = (t == 0) ? 1 : S_ITERS;
        for (int it = 0; it < niter; ++it) {
            const float* hcur = sh_hs[p];
            float h8[8];
            #pragma unroll
            for (int q = 0; q < 8; ++q) h8[q] = hcur[lane + 64 * q];
            for (int s = wave; s <= t; s += 8) {
                float d = 0.f;
                if (s == t) {
                    #pragma unroll
                    for (int q = 0; q < 8; ++q) d = fmaf(h8[q], h8[q], d);
                } else {
                    const float* vr = sh_hist[s];
                    #pragma unroll
                    for (int q = 0; q < 8; ++q) d = fmaf(vr[lane + 64 * q], h8[q], d);
                }
                #pragma unroll
                for (int off = 32; off > 0; off >>= 1) d += __shfl_xor(d, off, 64);
                if (lane == 0) sh_dot[s] = d;
            }
            __syncthreads();
            float dl = 0.f, w_l = 0.f;
            if (lane < t) { dl = sh_dot[lane]; w_l = sh_coef[lane] * dl; }
            float gsum = 0.f, Ah = 0.f;
            for (int s = 0; s < t; ++s) {
                const float ws = sh_coef[s] * sh_dot[s];
                gsum = fmaf(ws, sh_G[s][lane], gsum);
                Ah   = fmaf(ws, sh_hist[s][tid], Ah);
            }
            float pa = w_l * dl, pb = w_l * gsum;
            #pragma unroll
            for (int off = 32; off > 0; off >>= 1) {
                pa += __shfl_xor(pa, off, 64);
                pb += __shfl_xor(pb, off, 64);
            }
            const float n1 = fmaxf(sqrtf(sh_dot[t]), EPS_N);
            const float n2 = fmaxf(sqrtf(fmaxf(pb, 0.f)), EPS_N);
            float R = fminf(fmaxf(pa / (n1 * n2), 0.f), 1.f);
            const float alpha = 1.f - __powf(1.f - R, kpow);
            const float y = (1.f - alpha * alpha) * hbase_i + alpha * Ah;
            float q0 = y, q1 = y * y;
            #pragma unroll
            for (int off = 32; off > 0; off >>= 1) {
                q0 += __shfl_xor(q0, off, 64);
                q1 += __shfl_xor(q1, off, 64);
            }
            if (lane == 0) sh_red[wave] = make_float2(q0, q1);
            __syncthreads();
            float s0 = 0.f, s1 = 0.f;
            #pragma unroll
            for (int w = 0; w < 8; ++w) { const float2 r = sh_red[w]; s0 += r.x; s1 += r.y; }
            const float mean = s0 * (1.f / DHI);
            const float var  = fmaf(s1, 1.f / DHI, -mean * mean);
            const float rstd = rsqrtf(var + LN_EPS);
            hs_i = fmaxf(fmaf((y - mean) * rstd, g_r, bt_r), 0.f);
            p ^= 1; sh_hs[p][tid] = hs_i;
            if (it == niter - 1 && t + 1 < T_STEPS && tid < DGI)
                sh_z[tid] = z_seq[((size_t)(t + 1) * BATCH + b) * DGI + tid];
            __syncthreads();
        }

        if (t < T_STEPS - 1) {
            const float* hcur = sh_hs[p];
            float h8[8];
            #pragma unroll
            for (int q = 0; q < 8; ++q) h8[q] = hcur[lane + 64 * q];
            for (int s = wave; s <= t; s += 8) {
                float d = 0.f;
                if (s == t) {
                    #pragma unroll
                    for (int q = 0; q < 8; ++q) d = fmaf(h8[q], h8[q], d);
                } else {
                    const float* vr = sh_hist[s];
                    #pragma unroll
                    for (int q = 0; q < 8; ++q) d = fmaf(vr[lane + 64 * q], h8[q], d);
                }
                #pragma unroll
                for (int off = 32; off > 0; off >>= 1) d += __shfl_xor(d, off, 64);
                if (lane == 0) {
                    if (s == t) { sh_G[t][t] = d; sh_coef[t] = ETA / (d + EPS_A); }
                    else        { sh_G[t][s] = d; sh_G[s][t] = d; }
                }
            }
            if (tid < t) sh_coef[tid] *= LAMBDA;
            sh_hist[t][tid] = hs_i;
        } else {
            out[(size_t)b * DHI + tid] = hs_i;
        }
    }
}

extern "C" void kernel_launch(void* const* d_in, const int* in_sizes, int n_in,
                              void* d_out, int out_size, void* d_ws, size_t ws_size,
                              hipStream_t stream) {
    const float* z_seq    = (const float*)d_in[0];
    const float* W_h      = (const float*)d_in[1];
    const float* W_g      = (const float*)d_in[2];
    const float* b_h      = (const float*)d_in[3];
    const float* gamma    = (const float*)d_in[4];
    const float* beta     = (const float*)d_in[5];
    const float* alpha_fw = (const float*)d_in[6];
    float* out = (float*)d_out;

    const size_t zp_elems  = (size_t)BATCH * T_STEPS * DHI;  // 6 MB fp32
    const size_t wgt_elems = (size_t)DGI * DHI;              // 512 KB fp32
    const size_t p_elems   = (size_t)(DHI / 2) * DHI;        // 512 KB u32
    const size_t needed = (zp_elems + wgt_elems) * sizeof(float)
                        + p_elems * sizeof(unsigned int);
    if (ws_size >= needed) {
        float* zp  = (float*)d_ws;
        float* WgT = zp + zp_elems;
        unsigned int* P = (unsigned int*)(WgT + wgt_elems);
        prep_k<<<384, 512, 0, stream>>>(W_h, P, W_g, WgT);
        zproj_k<<<dim3(BATCH, T_STEPS / 8), 512, 0, stream>>>(z_seq, WgT, zp);
        rnn_v4<<<BATCH, 512, 0, stream>>>(zp, P, b_h, gamma, beta, alpha_fw, out);
    } else {
        corernn_fb<<<BATCH, 512, 0, stream>>>(z_seq, W_h, W_g, b_h, gamma, beta,
                                              alpha_fw, out);
    }
}

// Round 12
// 354.222 us; speedup vs baseline: 1.0687x; 1.0687x over previous
//
#include <hip/hip_runtime.h>
#include <hip/hip_fp16.h>
#include <math.h>

#define T_STEPS 24
#define BATCH   128
#define DGI     256
#define DHI     512
#define S_ITERS 3
#define LAMBDA  0.95f
#define ETA     0.5f
#define EPS_A   1e-6f
#define LN_EPS  1e-5f
#define EPS_N   1e-6f
#define HIST_MAX 23
#define NG4      6    // ceil(24/4) groups of 4 s-slots
#define NPIN     24   // pinned weight uint4 per thread (96 VGPR)

// dot2: fp16x2 . fp16x2 + fp32 -> fp32
static __device__ __forceinline__ float dot2(unsigned int a, unsigned int b, float c) {
#if __has_builtin(__builtin_amdgcn_fdot2)
    typedef _Float16 h2v __attribute__((ext_vector_type(2)));
    return __builtin_amdgcn_fdot2(__builtin_bit_cast(h2v, a),
                                  __builtin_bit_cast(h2v, b), c, false);
#else
    const __half2 ha = __builtin_bit_cast(__half2, a);
    const __half2 hb = __builtin_bit_cast(__half2, b);
    const float2 fa = __half22float2(ha);
    const float2 fb = __half22float2(hb);
    return fmaf(fa.x, fb.x, fmaf(fa.y, fb.y, c));
#endif
}

static __device__ __forceinline__ unsigned int rdlane_u(unsigned int v, int l) {
#if __has_builtin(__builtin_amdgcn_readlane)
    return __builtin_amdgcn_readlane(v, l);
#else
    return __shfl((int)v, l, 64);
#endif
}

static __device__ __forceinline__ float wsum(float v) {
    #pragma unroll
    for (int off = 32; off > 0; off >>= 1) v += __shfl_xor(v, off, 64);
    return v;
}
static __device__ __forceinline__ float dot8(float4 a, float4 b, float4 c, float4 d) {
    float r = a.x * c.x;
    r = fmaf(a.y, c.y, r); r = fmaf(a.z, c.z, r); r = fmaf(a.w, c.w, r);
    r = fmaf(b.x, d.x, r); r = fmaf(b.y, d.y, r); r = fmaf(b.z, d.z, r);
    r = fmaf(b.w, d.w, r);
    return r;
}
static __device__ __forceinline__ float sum8(float4 a, float4 b) {
    return ((a.x + a.y) + (a.z + a.w)) + ((b.x + b.y) + (b.z + b.w));
}

// ---------------------------------------------------------------------------
// Merged prep: blocks 0..255 pack W_h fp16 pairs (P[j2*512+i]); blocks
// 256..383 transpose W_g tile-wise into WgT[j][i].
// ---------------------------------------------------------------------------
__global__ __launch_bounds__(512)
void prep_k(const float* __restrict__ Wh, unsigned int* __restrict__ P,
            const float* __restrict__ Wg, float* __restrict__ WgT) {
    __shared__ float tile[32][33];
    const int blk = blockIdx.x;
    if (blk < 256) {
        const int j2 = blk;
        const int i  = threadIdx.x;
        const float2 w = *(const float2*)(Wh + (size_t)i * DHI + 2 * j2);
        const __half2 h = __floats2half2_rn(w.x, w.y);
        P[(size_t)j2 * DHI + i] = __builtin_bit_cast(unsigned int, h);
    } else {
        const int tb = blk - 256;            // [0,128): 8 x 16 tile grid
        const int c0 = (tb & 7) * 32;        // j (DGI) tile
        const int r0 = (tb >> 3) * 32;       // i (DHI) tile
        const int tx = threadIdx.x & 31;
        const int ty = (threadIdx.x >> 5) & 7;
        const bool act = threadIdx.x < 256;
        if (act) {
            #pragma unroll
            for (int i = 0; i < 32; i += 8)
                tile[ty + i][tx] = Wg[(size_t)(r0 + ty + i) * DGI + (c0 + tx)];
        }
        __syncthreads();
        if (act) {
            #pragma unroll
            for (int i = 0; i < 32; i += 8)
                WgT[(size_t)(c0 + ty + i) * DHI + (r0 + tx)] = tile[tx][ty + i];
        }
    }
}

// ---------------------------------------------------------------------------
// Recurrence v5. One block per batch element, 512 threads, min 2 waves/EU
// (allows ~256 VGPR without spill).
// - in-kernel zproj: z staged transposed in the (not-yet-used) sh_hist
//   region; one coalesced pass over WgT -> 24 per-thread zp values ->
//   global zp (L2-resident) reused by the existing per-step prefetch.
// - GEMV: first NPIN=24 of each thread's 64 weight uint4 pinned in
//   registers (step-invariant; statically indexed), rest streamed from L2.
// ---------------------------------------------------------------------------
__global__ __launch_bounds__(512, 2)
void rnn_v5(const float* __restrict__ z_seq,
            float* __restrict__ zp,
            const float* __restrict__ WgT,
            const unsigned int* __restrict__ P,
            const float* __restrict__ b_h,
            const float* __restrict__ gamma,
            const float* __restrict__ beta,
            const float* __restrict__ alpha_fw,
            float* __restrict__ out) {
    __shared__ __align__(16) float  sh_hist[HIST_MAX][DHI];  // hist rows; z-stage at start
    __shared__ __align__(16) float4 sh_hT4[NG4][DHI];
    __shared__ __align__(16) float4 sh_G4[NG4][64];
    __shared__ __align__(16) float  sh_hs[2][DHI];
    __shared__ __align__(16) float  sh_hb[DHI];
    __shared__ __align__(16) float4 sh_part[4][128];
    __shared__ __align__(16) unsigned int sh_h2[DHI / 2];
    __shared__ __align__(16) float  sh_coef[32];
    __shared__ __align__(16) float  sh_dot[32];
    __shared__ __align__(16) float  sh_dhb[32];
    __shared__ __align__(16) float  sh_rsum[32];
    __shared__ float sh_misc[2];

    const int tid  = threadIdx.x;
    const int lane = tid & 63;
    const int wave = tid >> 6;
    const int b    = blockIdx.x;

    const float bh_r = b_h[tid];
    const float g_r  = gamma[tid];
    const float bt_r = beta[tid];

    float kpow;
    {
        const float a  = alpha_fw[0];
        const float ax = fabsf(a);
        const float sp = (ax > 20.f) ? ax : log1pf(expf(ax));
        kpow = (a >= 0.f) ? (1.f + sp) : (1.f / (1.f + sp));
    }

    // ---- init + z staging (transposed, stride-28 floats, in sh_hist region)
    {
        const float4 z4 = make_float4(0.f, 0.f, 0.f, 0.f);
        for (int i = tid; i < NG4 * DHI; i += DHI) ((float4*)sh_hT4)[i] = z4;
        if (tid < NG4 * 64) ((float4*)sh_G4)[tid] = z4;
        if (tid < 32) { sh_coef[tid] = 0.f; sh_dot[tid] = 0.f;
                        sh_dhb[tid]  = 0.f; sh_rsum[tid] = 0.f; }
        if (tid < 2) sh_misc[tid] = 0.f;
        float* shz = (float*)sh_hist;               // [j*28 + t]
        for (int idx = tid; idx < T_STEPS * DGI; idx += DHI) {
            const int t = idx >> 8, j = idx & 255;
            shz[j * 28 + t] = z_seq[((size_t)t * BATCH + b) * DGI + j];
        }
    }
    __syncthreads();

    // ---- in-kernel zproj: zacc[t] = sum_j WgT[j][tid] * z[t][j]
    float zv;
    {
        float zacc[T_STEPS];
        #pragma unroll
        for (int k = 0; k < T_STEPS; ++k) zacc[k] = 0.f;
        const float* shz = (const float*)sh_hist;
        #pragma unroll 4
        for (int j = 0; j < DGI; ++j) {
            const float w = WgT[(size_t)j * DHI + tid];   // coalesced b32
            const float4* zt4 = (const float4*)(shz + j * 28);
            #pragma unroll
            for (int g = 0; g < 6; ++g) {
                const float4 zq = zt4[g];                 // broadcast b128
                zacc[4 * g + 0] = fmaf(w, zq.x, zacc[4 * g + 0]);
                zacc[4 * g + 1] = fmaf(w, zq.y, zacc[4 * g + 1]);
                zacc[4 * g + 2] = fmaf(w, zq.z, zacc[4 * g + 2]);
                zacc[4 * g + 3] = fmaf(w, zq.w, zacc[4 * g + 3]);
            }
        }
        #pragma unroll
        for (int k = 0; k < T_STEPS; ++k)
            zp[((size_t)b * T_STEPS + k) * DHI + tid] = zacc[k];
        zv = zacc[0];
    }

    // ---- pinned GEMV weights (step-invariant, statically indexed)
    const int i4 = tid & 127;
    const int jg = tid >> 7;
    const uint4* __restrict__ wp = (const uint4*)P;
    const int wbase = (jg << 6) * 128 + i4;
    uint4 Wpre[NPIN];
    #pragma unroll
    for (int k = 0; k < NPIN; ++k) Wpre[k] = wp[wbase + k * 128];

    int   p = 0;
    float hs_i = 0.f, hbase_i = 0.f;
    const size_t zbase = (size_t)b * T_STEPS * DHI + tid;

    for (int t = 0; t < T_STEPS; ++t) {
        // ---- GEMV: h_base = b_h + Wh.h + Wg.z
        if (t > 0) {
            const unsigned int hreg = sh_h2[(jg << 6) | lane];
            float4 acc = make_float4(0.f, 0.f, 0.f, 0.f);
            #pragma unroll
            for (int jj = 0; jj < NPIN; ++jj) {           // register half
                const unsigned int hh = rdlane_u(hreg, jj);
                const uint4 wv = Wpre[jj];
                acc.x = dot2(wv.x, hh, acc.x);
                acc.y = dot2(wv.y, hh, acc.y);
                acc.z = dot2(wv.z, hh, acc.z);
                acc.w = dot2(wv.w, hh, acc.w);
            }
            #pragma unroll 8
            for (int jj = NPIN; jj < 64; ++jj) {          // streamed half
                const unsigned int hh = rdlane_u(hreg, jj);
                const uint4 wv = wp[wbase + jj * 128];
                acc.x = dot2(wv.x, hh, acc.x);
                acc.y = dot2(wv.y, hh, acc.y);
                acc.z = dot2(wv.z, hh, acc.z);
                acc.w = dot2(wv.w, hh, acc.w);
            }
            sh_part[jg][i4] = acc;
            __syncthreads();                              // barrier A
            const float* pp = (const float*)sh_part;
            hbase_i = bh_r + zv +
                      ((pp[tid] + pp[512 + tid]) + (pp[1024 + tid] + pp[1536 + tid]));
        } else {
            hbase_i = bh_r + zv;
        }
        sh_hb[tid] = hbase_i;
        hs_i = fmaxf(hbase_i, 0.f);
        p ^= 1;
        sh_hs[p][tid] = hs_i;
        __syncthreads();                                  // barrier 1

        if (t + 1 < T_STEPS) zv = zp[zbase + (size_t)(t + 1) * DHI];

        const int niter = (t == 0) ? 1 : S_ITERS;
        for (int it = 0; it < niter; ++it) {
            // ---- dots phase: wave-split over s in [0..t]
            {
                const float4* h4p = (const float4*)sh_hs[p];
                const float4 ha = h4p[lane], hc = h4p[64 + lane];
                float4 ba, bc;
                if (it == 0) {
                    const float4* b4p = (const float4*)sh_hb;
                    ba = b4p[lane]; bc = b4p[64 + lane];
                }
                for (int s = wave; s <= t; s += 8) {
                    if (s == t) {
                        float d = dot8(ha, hc, ha, hc);
                        if (it == 0) {
                            float s1 = sum8(ba, bc);
                            float s2 = dot8(ba, bc, ba, bc);
                            d = wsum(d); s1 = wsum(s1); s2 = wsum(s2);
                            if (lane == 0) { sh_dot[t] = d;
                                             sh_misc[0] = s1; sh_misc[1] = s2; }
                        } else {
                            d = wsum(d);
                            if (lane == 0) sh_dot[t] = d;
                        }
                    } else {
                        const float4* v4 = (const float4*)sh_hist[s];
                        const float4 va = v4[lane], vc = v4[64 + lane];
                        float d = dot8(va, vc, ha, hc);
                        if (it == 0) {
                            float e = dot8(va, vc, ba, bc);
                            d = wsum(d); e = wsum(e);
                            if (lane == 0) { sh_dot[s] = d; sh_dhb[s] = e; }
                        } else {
                            d = wsum(d);
                            if (lane == 0) sh_dot[s] = d;
                        }
                    }
                }
            }
            __syncthreads();                              // barrier 2

            // ---- scalar phase (algebraic LN)
            float pa = 0.f, SA = 0.f, SHA = 0.f, gsum = 0.f, Ah = 0.f;
            {
                const float4* c4 = (const float4*)sh_coef;
                const float4* d4 = (const float4*)sh_dot;
                const float4* e4 = (const float4*)sh_dhb;
                const float4* r4 = (const float4*)sh_rsum;
                const int ng = (t + 4) >> 2;
                for (int g = 0; g < ng; ++g) {
                    const float4 cc = c4[g], dd = d4[g], ee = e4[g], rr = r4[g];
                    const float4 gg = sh_G4[g][lane];
                    const float4 hv = sh_hT4[g][tid];
                    const float w0 = cc.x * dd.x, w1 = cc.y * dd.y;
                    const float w2 = cc.z * dd.z, w3 = cc.w * dd.w;
                    pa   = fmaf(w0, dd.x, fmaf(w1, dd.y, fmaf(w2, dd.z, fmaf(w3, dd.w, pa))));
                    SA   = fmaf(w0, rr.x, fmaf(w1, rr.y, fmaf(w2, rr.z, fmaf(w3, rr.w, SA))));
                    SHA  = fmaf(w0, ee.x, fmaf(w1, ee.y, fmaf(w2, ee.z, fmaf(w3, ee.w, SHA))));
                    gsum = fmaf(w0, gg.x, fmaf(w1, gg.y, fmaf(w2, gg.z, fmaf(w3, gg.w, gsum))));
                    Ah   = fmaf(w0, hv.x, fmaf(w1, hv.y, fmaf(w2, hv.z, fmaf(w3, hv.w, Ah))));
                }
            }
            const float wl = (lane < 32) ? sh_coef[lane] * sh_dot[lane] : 0.f;
            const float pb = wsum(wl * gsum);

            const float n1 = fmaxf(sqrtf(sh_dot[t]), EPS_N);
            const float n2 = fmaxf(sqrtf(fmaxf(pb, 0.f)), EPS_N);
            float R = pa / (n1 * n2);
            R = fminf(fmaxf(R, 0.f), 1.f);
            const float alpha = 1.f - __powf(1.f - R, kpow);
            const float c = 1.f - alpha * alpha;

            const float S1 = sh_misc[0], S2 = sh_misc[1];
            const float mean = (c * S1 + alpha * SA) * (1.f / DHI);
            float var = (c * c * S2 + 2.f * c * alpha * SHA + alpha * alpha * pb)
                        * (1.f / DHI) - mean * mean;
            var = fmaxf(var, 0.f);
            const float rstd = rsqrtf(var + LN_EPS);

            const float y = fmaf(c, hbase_i, alpha * Ah);
            hs_i = fmaxf(fmaf((y - mean) * rstd, g_r, bt_r), 0.f);
            p ^= 1;
            sh_hs[p][tid] = hs_i;
            if (it == niter - 1 && t + 1 < T_STEPS) {
                const float partner = __shfl_xor(hs_i, 1);
                if (!(tid & 1)) {
                    const __half2 h2 = __floats2half2_rn(hs_i, partner);
                    sh_h2[tid >> 1] = __builtin_bit_cast(unsigned int, h2);
                }
            }
            __syncthreads();                              // barrier 4
        }

        if (t < T_STEPS - 1) {
            // ---- append: Gram row + coef + rowsum + both hist layouts
            const float4* h4p = (const float4*)sh_hs[p];
            const float4 ha = h4p[lane], hc = h4p[64 + lane];
            for (int s = wave; s <= t; s += 8) {
                if (s == t) {
                    float d  = dot8(ha, hc, ha, hc);
                    float rs = sum8(ha, hc);
                    d = wsum(d); rs = wsum(rs);
                    if (lane == 0) {
                        ((float*)&sh_G4[t >> 2][t])[t & 3] = d;
                        sh_coef[t] = ETA / (d + EPS_A);
                        sh_rsum[t] = rs;
                    }
                } else {
                    const float4* v4 = (const float4*)sh_hist[s];
                    const float4 va = v4[lane], vc = v4[64 + lane];
                    float d = dot8(va, vc, ha, hc);
                    d = wsum(d);
                    if (lane == 0) {
                        ((float*)&sh_G4[t >> 2][s])[t & 3] = d;
                        ((float*)&sh_G4[s >> 2][t])[s & 3] = d;
                    }
                }
            }
            if (tid < t) sh_coef[tid] *= LAMBDA;
            sh_hist[t][tid] = hs_i;
            ((float*)&sh_hT4[t >> 2][tid])[t & 3] = hs_i;
        } else {
            out[(size_t)b * DHI + tid] = hs_i;
        }
    }
}

// ---------------------------------------------------------------------------
// Fallback (ws too small): self-contained fp32 path (known-good).
// ---------------------------------------------------------------------------
__global__ __launch_bounds__(512)
void corernn_fb(const float* __restrict__ z_seq, const float* __restrict__ Wh,
                const float* __restrict__ Wg, const float* __restrict__ b_h,
                const float* __restrict__ gamma, const float* __restrict__ beta,
                const float* __restrict__ alpha_fw, float* __restrict__ out) {
    __shared__ __align__(16) float sh_hist[HIST_MAX][DHI];
    __shared__ __align__(16) float sh_hs[2][DHI];
    __shared__ __align__(16) float sh_G[HIST_MAX][64];
    __shared__ float  sh_coef[32];
    __shared__ float  sh_dot[32];
    __shared__ float2 sh_red[8];
    __shared__ __align__(16) float sh_z[DGI];

    const int tid  = threadIdx.x;
    const int lane = tid & 63;
    const int wave = tid >> 6;
    const int b    = blockIdx.x;
    const float bh_r = b_h[tid];
    const float g_r  = gamma[tid];
    const float bt_r = beta[tid];
    float kpow;
    {
        const float a  = alpha_fw[0];
        const float ax = fabsf(a);
        const float sp = (ax > 20.f) ? ax : log1pf(expf(ax));
        kpow = (a >= 0.f) ? (1.f + sp) : (1.f / (1.f + sp));
    }
    for (int i = tid; i < HIST_MAX * 64; i += DHI) ((float*)sh_G)[i] = 0.f;
    if (tid < DGI) sh_z[tid] = z_seq[(size_t)b * DGI + tid];
    __syncthreads();

    int p = 0;
    float hs_i = 0.f, hbase_i = 0.f;
    for (int t = 0; t < T_STEPS; ++t) {
        float a0 = bh_r, a1 = 0.f, a2 = 0.f, a3 = 0.f;
        {
            const float4* wrow = (const float4*)(Wg + (size_t)tid * DGI);
            const float4* z4   = (const float4*)sh_z;
            #pragma unroll 4
            for (int j4 = 0; j4 < DGI / 4; ++j4) {
                const float4 w = wrow[j4]; const float4 h = z4[j4];
                a0 = fmaf(w.x, h.x, a0); a1 = fmaf(w.y, h.y, a1);
                a2 = fmaf(w.z, h.z, a2); a3 = fmaf(w.w, h.w, a3);
            }
        }
        if (t > 0) {
            const float4* wrow = (const float4*)(Wh + (size_t)tid * DHI);
            const float4* h4   = (const float4*)sh_hs[p];
            #pragma unroll 4
            for (int j4 = 0; j4 < DHI / 4; ++j4) {
                const float4 w = wrow[j4]; const float4 h = h4[j4];
                a0 = fmaf(w.x, h.x, a0); a1 = fmaf(w.y, h.y, a1);
                a2 = fmaf(w.z, h.z, a2); a3 = fmaf(w.w, h.w, a3);
            }
        }
        hbase_i = (a0 + a1) + (a2 + a3);
        hs_i = fmaxf(hbase_i, 0.f);
        p ^= 1; sh_hs[p][tid] = hs_i;
        __syncthreads();

        const int niter = (t == 0) ? 1 : S_ITERS;
        for (int it = 0; it < niter; ++it) {
            const float* hcur = sh_hs[p];
            float h8[8];
            #pragma unroll
            for (int q = 0; q < 8; ++q) h8[q] = hcur[lane + 64 * q];
            for (int s = wave; s <= t; s += 8) {
                float d = 0.f;
                if (s == t) {
                    #pragma unroll
                    for (int q = 0; q < 8; ++q) d = fmaf(h8[q], h8[q], d);
                } else {
                    const float* vr = sh_hist[s];
                    #pragma unroll
                    for (int q = 0; q < 8; ++q) d = fmaf(vr[lane + 64 * q], h8[q], d);
                }
                #pragma unroll
                for (int off = 32; off > 0; off >>= 1) d += __shfl_xor(d, off, 64);
                if (lane == 0) sh_dot[s] = d;
            }
            __syncthreads();
            float dl = 0.f, w_l = 0.f;
            if (lane < t) { dl = sh_dot[lane]; w_l = sh_coef[lane] * dl; }
            float gsum = 0.f, Ah = 0.f;
            for (int s = 0; s < t; ++s) {
                const float ws = sh_coef[s] * sh_dot[s];
                gsum = fmaf(ws, sh_G[s][lane], gsum);
                Ah   = fmaf(ws, sh_hist[s][tid], Ah);
            }
            float pa = w_l * dl, pb = w_l * gsum;
            #pragma unroll
            for (int off = 32; off > 0; off >>= 1) {
                pa += __shfl_xor(pa, off, 64);
                pb += __shfl_xor(pb, off, 64);
            }
            const float n1 = fmaxf(sqrtf(sh_dot[t]), EPS_N);
            const float n2 = fmaxf(sqrtf(fmaxf(pb, 0.f)), EPS_N);
            float R = fminf(fmaxf(pa / (n1 * n2), 0.f), 1.f);
            const float alpha = 1.f - __powf(1.f - R, kpow);
            const float y = (1.f - alpha * alpha) * hbase_i + alpha * Ah;
            float q0 = y, q1 = y * y;
            #pragma unroll
            for (int off = 32; off > 0; off >>= 1) {
                q0 += __shfl_xor(q0, off, 64);
                q1 += __shfl_xor(q1, off, 64);
            }
            if (lane == 0) sh_red[wave] = make_float2(q0, q1);
            __syncthreads();
            float s0 = 0.f, s1 = 0.f;
            #pragma unroll
            for (int w = 0; w < 8; ++w) { const float2 r = sh_red[w]; s0 += r.x; s1 += r.y; }
            const float mean = s0 * (1.f / DHI);
            const float var  = fmaf(s1, 1.f / DHI, -mean * mean);
            const float rstd = rsqrtf(var + LN_EPS);
            hs_i = fmaxf(fmaf((y - mean) * rstd, g_r, bt_r), 0.f);
            p ^= 1; sh_hs[p][tid] = hs_i;
            if (it == niter - 1 && t + 1 < T_STEPS && tid < DGI)
                sh_z[tid] = z_seq[((size_t)(t + 1) * BATCH + b) * DGI + tid];
            __syncthreads();
        }

        if (t < T_STEPS - 1) {
            const float* hcur = sh_hs[p];
            float h8[8];
            #pragma unroll
            for (int q = 0; q < 8; ++q) h8[q] = hcur[lane + 64 * q];
            for (int s = wave; s <= t; s += 8) {
                float d = 0.f;
                if (s == t) {
                    #pragma unroll
                    for (int q = 0; q < 8; ++q) d = fmaf(h8[q], h8[q], d);
                } else {
                    const float* vr = sh_hist[s];
                    #pragma unroll
                    for (int q = 0; q < 8; ++q) d = fmaf(vr[lane + 64 * q], h8[q], d);
                }
                #pragma unroll
                for (int off = 32; off > 0; off >>= 1) d += __shfl_xor(d, off, 64);
                if (lane == 0) {
                    if (s == t) { sh_G[t][t] = d; sh_coef[t] = ETA / (d + EPS_A); }
                    else        { sh_G[t][s] = d; sh_G[s][t] = d; }
                }
            }
            if (tid < t) sh_coef[tid] *= LAMBDA;
            sh_hist[t][tid] = hs_i;
        } else {
            out[(size_t)b * DHI + tid] = hs_i;
        }
    }
}

extern "C" void kernel_launch(void* const* d_in, const int* in_sizes, int n_in,
                              void* d_out, int out_size, void* d_ws, size_t ws_size,
                              hipStream_t stream) {
    const float* z_seq    = (const float*)d_in[0];
    const float* W_h      = (const float*)d_in[1];
    const float* W_g      = (const float*)d_in[2];
    const float* b_h      = (const float*)d_in[3];
    const float* gamma    = (const float*)d_in[4];
    const float* beta     = (const float*)d_in[5];
    const float* alpha_fw = (const float*)d_in[6];
    float* out = (float*)d_out;

    const size_t zp_elems  = (size_t)BATCH * T_STEPS * DHI;  // 6 MB fp32
    const size_t wgt_elems = (size_t)DGI * DHI;              // 512 KB fp32
    const size_t p_elems   = (size_t)(DHI / 2) * DHI;        // 512 KB u32
    const size_t needed = (zp_elems + wgt_elems) * sizeof(float)
                        + p_elems * sizeof(unsigned int);
    if (ws_size >= needed) {
        float* zp  = (float*)d_ws;
        float* WgT = zp + zp_elems;
        unsigned int* P = (unsigned int*)(WgT + wgt_elems);
        prep_k<<<384, 512, 0, stream>>>(W_h, P, W_g, WgT);
        rnn_v5<<<BATCH, 512, 0, stream>>>(z_seq, zp, WgT, P, b_h, gamma, beta,
                                          alpha_fw, out);
    } else {
        corernn_fb<<<BATCH, 512, 0, stream>>>(z_seq, W_h, W_g, b_h, gamma, beta,
                                              alpha_fw, out);
    }
}